// Round 17
// baseline (2490.609 us; speedup 1.0000x reference)
//
#include <hip/hip_runtime.h>
#include <hip/hip_bf16.h>

#define Bb 64
#define Tt 256
#define Ii 256
#define Hh 512
#define Cc 1000
#define SENT 0x7F80u  // bf16 +inf; |h|<1 so never produced

typedef float f4 __attribute__((ext_vector_type(4)));
typedef short s8 __attribute__((ext_vector_type(8)));
typedef unsigned long long u64;

__device__ __forceinline__ unsigned short f2bf(float f) {
  union { float f; unsigned u; } v; v.f = f;
  return (unsigned short)((v.u + 0x7FFFu + ((v.u >> 16) & 1u)) >> 16);
}
__device__ __forceinline__ float sigf(float x) {
  return __builtin_amdgcn_rcpf(1.f + __expf(-x));
}
__device__ __forceinline__ float tanhs(float x) {
  float ax = fabsf(x);
  float e = __expf(-2.f * ax);
  float r = (1.f - e) * __builtin_amdgcn_rcpf(1.f + e);
  return copysignf(r, x);
}

// LLC load (bypass L1+L2) — R8/R13-proven; sentinel re-reads never see stale cache.
__device__ __forceinline__ s8 ld128_llc(const unsigned short* p) {
  s8 v;
  asm volatile("global_load_dwordx4 %0, %1, off sc0 sc1" : "=&v"(v) : "v"(p) : "memory");
  return v;
}
#define VMCNT0 asm volatile("s_waitcnt vmcnt(0)" ::: "memory")
#define SBAR __builtin_amdgcn_sched_barrier(0)

__device__ __forceinline__ bool chk(s8 v) {  // both 8B halves non-sentinel
  return ((unsigned short)v[0] != (unsigned short)SENT) &
         ((unsigned short)v[4] != (unsigned short)SENT);
}

struct PT {
  const float* x;
  const float* Whh[3]; const float* Wih[3];
  const float* bih[3]; const float* bhh[3];
  const float* fcw;
  float* outbuf;
  unsigned short* y[3];
  unsigned* fl;    // [(L*32+s)*4+w]*16 per-producer flags (t+1), fire-and-forget
  unsigned* fcfl;  // [(s*4+w)]*16 layer-2 drained flags (every 8th step)
};

__global__ void zero_sync(unsigned* f) {
  int i = blockIdx.x * 256 + threadIdx.x;
  if (i < 8192) f[i] = 0;
}

// sentinel pre-fill of all y buffers (agent scope -> LLC)
__global__ void fill_y(u64* p) {
  const u64 pat = 0x7F807F807F807F80ull;
  size_t g = (size_t)blockIdx.x * 256 + threadIdx.x;
#pragma unroll
  for (int i = 0; i < 16; ++i)
    __hip_atomic_store(p + g + (size_t)i * 393216, pat, __ATOMIC_RELAXED,
                       __HIP_MEMORY_SCOPE_AGENT);
}

__global__ void bias_init_kernel(const float* __restrict__ fcb, float* __restrict__ out) {
  int i = blockIdx.x * 256 + threadIdx.x;
  if (i < Bb * Cc) out[i] = fcb[i % Cc];
}

// grid 256, 1 block/CU. bid<96: LSTM (L=bid>>5, s=bid&31, 16 dims/slice, per-wave
// batch chains). bid>=96: FC (160 blocks, tiles gated on fcfl).
// R13 protocol exactly (flags as hints, sentinel verify as truth, fire-and-forget
// producers) + ONE addition: cross-layer y[t+1] rows are PREFETCHED at step end
// via compiler-managed agent atomic loads (fly across the loop boundary); at use
// they are sentinel-verified, with R13's flag-poll + selective asm re-read as the
// fallback. h path untouched. One deferred-wait asm array max (R14 lesson).
__launch_bounds__(256, 1)
__global__ void mega_kernel(PT p) {
  const int bid = blockIdx.x;
  const int tid = threadIdx.x;
  const int lane = tid & 63;
  const int w = tid >> 6;
  const int q = lane >> 4;
  const int c = lane & 15;
  const int b = 16 * w + c;

  __shared__ unsigned short Whl[64 * 512];  // 64 KB swizzled (recurrent)
  __shared__ unsigned short Wil[64 * 512];  // 64 KB (input; L0 uses 64x256)

  if (bid < 96) {
    const int L = bid >> 5;
    const int s = bid & 31;
    const int n0 = s * 16;

    const int Kin = (L == 0) ? Ii : Hh;
    {  // stage: LDS row r=tt*16+rho <- gate-row (rho&3)*H + n0 + 4*(rho>>2) + tt
      const float* src = p.Whh[L];
      for (int idx = tid; idx < 64 * 64; idx += 256) {
        int r = idx >> 6, kk = (idx & 63) << 3;
        int rho = r & 15, tt = r >> 4;
        int j = (rho & 3) * Hh + n0 + 4 * (rho >> 2) + tt;
        const float* sr = src + (size_t)j * Hh + kk;
        s8 tv;
#pragma unroll
        for (int e = 0; e < 8; ++e) tv[e] = (short)f2bf(sr[e]);
        int byt = ((r * 512 + kk) * 2) ^ ((r & 7) << 4);
        *(s8*)((char*)Whl + byt) = tv;
      }
      const float* si = p.Wih[L];
      const int kd8 = Kin >> 3;
      for (int idx = tid; idx < 64 * kd8; idx += 256) {
        int r = idx / kd8, kk = (idx - r * kd8) << 3;
        int rho = r & 15, tt = r >> 4;
        int j = (rho & 3) * Hh + n0 + 4 * (rho >> 2) + tt;
        const float* sr = si + (size_t)j * Kin + kk;
        s8 tv;
#pragma unroll
        for (int e = 0; e < 8; ++e) tv[e] = (short)f2bf(sr[e]);
        int byt = ((r * Kin + kk) * 2) ^ ((r & 7) << 4);
        *(s8*)((char*)Wil + byt) = tv;
      }
    }

    f4 bias[4];
#pragma unroll
    for (int tt = 0; tt < 4; ++tt)
#pragma unroll
      for (int g = 0; g < 4; ++g) {
        int bi = g * Hh + n0 + 4 * q + tt;  // lane (q,c) tile tt -> dim n0+4q+tt
        bias[tt][g] = p.bih[L][bi] + p.bhh[L][bi];
      }
    float cst[4] = {0.f, 0.f, 0.f, 0.f};
    __syncthreads();

    const int aswz = (c & 7) << 4;
    unsigned short* yl = p.y[L];
    const unsigned short* ylow = (L > 0) ? p.y[L - 1] : (const unsigned short*)0;
    unsigned* flin = (L > 0) ? p.fl + ((L - 1) * 32) * 4 * 16 : (unsigned*)0;
    unsigned* flown = p.fl + (L * 32) * 4 * 16;
    unsigned* myfl = p.fl + ((L * 32 + s) * 4 + w) * 16;

    u64 py[32];  // cross-layer prefetch buffer (compiler-managed loads)

    for (int t = 0; t < Tt; ++t) {
      f4 acc[4];
#pragma unroll
      for (int tt = 0; tt < 4; ++tt) acc[tt] = bias[tt];

      // ---- input acquisition + GEMM ----
      if (L == 0) {
        const float* xr = p.x + ((size_t)b * Tt + t) * Ii + 8 * q;
#pragma unroll
        for (int kc = 0; kc < 8; ++kc) {
          f4 xa = *(const f4*)(xr + kc * 32);
          f4 xc = *(const f4*)(xr + kc * 32 + 4);
          s8 xb;
#pragma unroll
          for (int e = 0; e < 4; ++e) { xb[e] = (short)f2bf(xa[e]); xb[e + 4] = (short)f2bf(xc[e]); }
#pragma unroll
          for (int tt = 0; tt < 4; ++tt) {
            int byt = (((tt * 16 + c) * 256 + kc * 32 + 8 * q) * 2) ^ aswz;
            s8 wa = *(const s8*)((const char*)Wil + byt);
            acc[tt] = __builtin_amdgcn_mfma_f32_16x16x32_bf16(wa, xb, acc[tt], 0, 0, 0);
          }
        }
      } else {
        const unsigned short* yr = ylow + ((size_t)b * Tt + t) * Hh + 8 * q;
        s8 yb[16];
        unsigned bad;
        if (t > 0) {  // consume prefetch (issued at end of step t-1)
          bad = 0;
#pragma unroll
          for (int kc = 0; kc < 16; ++kc) {
            union { u64 u[2]; s8 v8; } cv;
            cv.u[0] = py[2 * kc]; cv.u[1] = py[2 * kc + 1];
            yb[kc] = cv.v8;
            if (!chk(cv.v8)) bad |= (1u << kc);
          }
        } else {
          bad = 0xFFFFu;  // no prefetch yet: full fallback (== R13 initial read)
        }
        if (!__all(bad == 0)) {
          // fallback: flag poll, then selective asm re-read + verify (R13)
          while (!__all(lane < 32
                            ? __hip_atomic_load(flin + (lane * 4 + w) * 16, __ATOMIC_RELAXED,
                                                __HIP_MEMORY_SCOPE_AGENT) >= (unsigned)(t + 1)
                            : true))
            __builtin_amdgcn_s_sleep(1);
          asm volatile("" ::: "memory");
          while (1) {
#pragma unroll
            for (int kc = 0; kc < 16; ++kc)
              if (bad & (1u << kc)) yb[kc] = ld128_llc(yr + kc * 32);
            VMCNT0; SBAR;
            bad = 0;
#pragma unroll
            for (int kc = 0; kc < 16; ++kc)
              if (!chk(yb[kc])) bad |= (1u << kc);
            if (__all(bad == 0)) break;
            __builtin_amdgcn_s_sleep(1);
          }
        }
#pragma unroll
        for (int tt = 0; tt < 4; ++tt)
#pragma unroll
          for (int kc = 0; kc < 16; ++kc) {
            int byt = (((tt * 16 + c) * 512 + kc * 32 + 8 * q) * 2) ^ aswz;
            s8 wa = *(const s8*)((const char*)Wil + byt);
            acc[tt] = __builtin_amdgcn_mfma_f32_16x16x32_bf16(wa, yb[kc], acc[tt], 0, 0, 0);
          }
      }

      // ---- h[t-1]: R13 exact (poll flags -> bulk asm read -> verify -> GEMM) ----
      if (t > 0) {
        const unsigned short* hr = yl + ((size_t)b * Tt + (t - 1)) * Hh + 8 * q;
        s8 hb[16];
        while (!__all(lane < 32
                          ? __hip_atomic_load(flown + (lane * 4 + w) * 16, __ATOMIC_RELAXED,
                                              __HIP_MEMORY_SCOPE_AGENT) >= (unsigned)t
                          : true))
          __builtin_amdgcn_s_sleep(1);
        asm volatile("" ::: "memory");
#pragma unroll
        for (int kc = 0; kc < 16; ++kc) hb[kc] = ld128_llc(hr + kc * 32);
        VMCNT0; SBAR;
        while (1) {
          unsigned bad = 0;
#pragma unroll
          for (int kc = 0; kc < 16; ++kc)
            if (!chk(hb[kc])) bad |= (1u << kc);
          if (__all(bad == 0)) break;
          __builtin_amdgcn_s_sleep(1);
#pragma unroll
          for (int kc = 0; kc < 16; ++kc)
            if (bad & (1u << kc)) hb[kc] = ld128_llc(hr + kc * 32);
          VMCNT0; SBAR;
        }
#pragma unroll
        for (int tt = 0; tt < 4; ++tt)
#pragma unroll
          for (int kc = 0; kc < 16; ++kc) {
            int byt = (((tt * 16 + c) * 512 + kc * 32 + 8 * q) * 2) ^ aswz;
            s8 wa = *(const s8*)((const char*)Whl + byt);
            acc[tt] = __builtin_amdgcn_mfma_f32_16x16x32_bf16(wa, hb[kc], acc[tt], 0, 0, 0);
          }
      }

      // ---- pointwise: lane (q,c) dims n0+4q+tt, gates {i,f,g,o}=acc[tt][0..3] ----
      unsigned short hu[4];
#pragma unroll
      for (int tt = 0; tt < 4; ++tt) {
        float ii = sigf(acc[tt][0]), ff = sigf(acc[tt][1]);
        float gg = tanhs(acc[tt][2]), oo = sigf(acc[tt][3]);
        cst[tt] = ff * cst[tt] + ii * gg;
        hu[tt] = f2bf(oo * tanhs(cst[tt]));
      }
      u64 hv = (u64)hu[0] | ((u64)hu[1] << 16) | ((u64)hu[2] << 32) | ((u64)hu[3] << 48);
      u64* dst = (u64*)(yl + ((size_t)b * Tt + t) * Hh + n0 + 4 * q);
      // fire-and-forget: h store + flag, NO drain (consumers verify sentinels)
      __hip_atomic_store(dst, hv, __ATOMIC_RELAXED, __HIP_MEMORY_SCOPE_AGENT);
      if (lane == 0)
        __hip_atomic_store(myfl, (unsigned)(t + 1), __ATOMIC_RELAXED, __HIP_MEMORY_SCOPE_AGENT);
      // layer-2 only: amortized drained release for FC (sound gate, every 8 steps)
      if (L == 2 && (t & 7) == 7) {
        VMCNT0;
        if (lane == 0)
          __hip_atomic_store(p.fcfl + (s * 4 + w) * 16, (unsigned)(t + 1), __ATOMIC_RELAXED,
                             __HIP_MEMORY_SCOPE_AGENT);
      }
      // ---- prefetch y[t+1] (compiler-managed; flies across the loop boundary) ----
      if (L > 0 && t + 1 < Tt) {
        const u64* pf = (const u64*)(ylow + ((size_t)b * Tt + (t + 1)) * Hh + 8 * q);
#pragma unroll
        for (int e = 0; e < 32; ++e)
          py[e] = __hip_atomic_load(pf + (e >> 1) * 8 + (e & 1), __ATOMIC_RELAXED,
                                    __HIP_MEMORY_SCOPE_AGENT);
      }
    }
  } else {
    // ======================= FC role =======================
    const int fcid = bid - 96;
    const int KT = Tt * Hh;
    const unsigned short* y2 = p.y[2];
    for (int ti = fcid; ti < 1024; ti += 160) {
      const int kch = ti >> 5, ct = ti & 31;
      const unsigned tneed1 = (unsigned)(kch * 8 + 8);  // fcfl value releasing this k-chunk
      bool ok;
      do {
        unsigned v = 0xFFFFFFFFu;
        if (lane < 32) {
          unsigned mn = 0xFFFFFFFFu;
#pragma unroll
          for (int ww = 0; ww < 4; ++ww) {
            unsigned vv = __hip_atomic_load(p.fcfl + (lane * 4 + ww) * 16, __ATOMIC_RELAXED,
                                            __HIP_MEMORY_SCOPE_AGENT);
            mn = mn < vv ? mn : vv;
          }
          v = mn;
        }
        ok = __all(v >= tneed1);
        if (!ok) __builtin_amdgcn_s_sleep(16);
      } while (!ok);
      asm volatile("" ::: "memory");

      const int kbase = kch * 4096 + q * 8;
      const int c0 = ct * 32 + c;
      const int c1 = c0 + 16;
      const bool v0 = (c0 < Cc), v1 = (c1 < Cc);
      const float* w0 = p.fcw + (size_t)c0 * KT;
      const float* w1 = p.fcw + (size_t)c1 * KT;
      const unsigned short* yr = y2 + (size_t)b * KT;
      f4 a0 = {0.f, 0.f, 0.f, 0.f}, a1 = {0.f, 0.f, 0.f, 0.f};
      for (int kk = 0; kk < 4096; kk += 32) {
        const int k = kbase + kk;
        s8 bf = *(const s8*)(yr + k);
        s8 wa0 = {0, 0, 0, 0, 0, 0, 0, 0}, wa1 = {0, 0, 0, 0, 0, 0, 0, 0};
        if (v0) {
#pragma unroll
          for (int qq = 0; qq < 8; ++qq) wa0[qq] = (short)f2bf(w0[k + qq]);
        }
        if (v1) {
#pragma unroll
          for (int qq = 0; qq < 8; ++qq) wa1[qq] = (short)f2bf(w1[k + qq]);
        }
        a0 = __builtin_amdgcn_mfma_f32_16x16x32_bf16(wa0, bf, a0, 0, 0, 0);
        a1 = __builtin_amdgcn_mfma_f32_16x16x32_bf16(wa1, bf, a1, 0, 0, 0);
      }
      const int rr = q * 4;
#pragma unroll
      for (int qq = 0; qq < 4; ++qq) {
        int ca = ct * 32 + rr + qq;
        if (ca < Cc) atomicAdd(p.outbuf + (size_t)b * Cc + ca, a0[qq]);
        int cb2 = ca + 16;
        if (cb2 < Cc) atomicAdd(p.outbuf + (size_t)b * Cc + cb2, a1[qq]);
      }
    }
  }
}

extern "C" void kernel_launch(void* const* d_in, const int* in_sizes, int n_in,
                              void* d_out, int out_size, void* d_ws, size_t ws_size,
                              hipStream_t stream) {
  PT p;
  p.x = (const float*)d_in[0];
  p.Wih[0] = (const float*)d_in[1];  p.Whh[0] = (const float*)d_in[2];
  p.bih[0] = (const float*)d_in[3];  p.bhh[0] = (const float*)d_in[4];
  p.Wih[1] = (const float*)d_in[5];  p.Whh[1] = (const float*)d_in[6];
  p.bih[1] = (const float*)d_in[7];  p.bhh[1] = (const float*)d_in[8];
  p.Wih[2] = (const float*)d_in[9];  p.Whh[2] = (const float*)d_in[10];
  p.bih[2] = (const float*)d_in[11]; p.bhh[2] = (const float*)d_in[12];
  p.fcw = (const float*)d_in[13];
  const float* fcb = (const float*)d_in[14];
  p.outbuf = (float*)d_out;

  char* ws = (char*)d_ws;
  p.fl = (unsigned*)ws;                 // 24 KB spread flags
  p.fcfl = p.fl + 6144;                 // 8 KB fc gates
  const size_t ysz = (size_t)Bb * Tt * Hh;
  unsigned short* y0 = (unsigned short*)(ws + 65536);
  p.y[0] = y0;
  p.y[1] = y0 + ysz;
  p.y[2] = y0 + 2 * ysz;

  zero_sync<<<32, 256, 0, stream>>>(p.fl);
  fill_y<<<1536, 256, 0, stream>>>((u64*)y0);  // 3*ysz*2 B = 6291456 u64 exactly
  bias_init_kernel<<<250, 256, 0, stream>>>(fcb, (float*)d_out);
  mega_kernel<<<256, 256, 0, stream>>>(p);
}

// Round 18
// 1795.406 us; speedup vs baseline: 1.3872x; 1.3872x over previous
//
#include <hip/hip_runtime.h>
#include <hip/hip_bf16.h>

#define Bb 64
#define Tt 256
#define Ii 256
#define Hh 512
#define Cc 1000
#define SENT 0x7F80u  // bf16 +inf; |h|<1 so never produced

typedef float f4 __attribute__((ext_vector_type(4)));
typedef short s8 __attribute__((ext_vector_type(8)));
typedef unsigned long long u64;

__device__ __forceinline__ unsigned short f2bf(float f) {
  union { float f; unsigned u; } v; v.f = f;
  return (unsigned short)((v.u + 0x7FFFu + ((v.u >> 16) & 1u)) >> 16);
}
__device__ __forceinline__ float sigf(float x) {
  return __builtin_amdgcn_rcpf(1.f + __expf(-x));
}
__device__ __forceinline__ float tanhs(float x) {
  float ax = fabsf(x);
  float e = __expf(-2.f * ax);
  float r = (1.f - e) * __builtin_amdgcn_rcpf(1.f + e);
  return copysignf(r, x);
}

// LLC load (bypass L1+L2) — R8/R13-proven; sentinel re-reads never see stale cache.
__device__ __forceinline__ s8 ld128_llc(const unsigned short* p) {
  s8 v;
  asm volatile("global_load_dwordx4 %0, %1, off sc0 sc1" : "=&v"(v) : "v"(p) : "memory");
  return v;
}
#define VMCNT0 asm volatile("s_waitcnt vmcnt(0)" ::: "memory")
#define SBAR __builtin_amdgcn_sched_barrier(0)

__device__ __forceinline__ bool chk(s8 v) {  // both 8B halves non-sentinel
  return ((unsigned short)v[0] != (unsigned short)SENT) &
         ((unsigned short)v[4] != (unsigned short)SENT);
}

struct PT {
  const float* x;
  const float* Whh[3]; const float* Wih[3];
  const float* bih[3]; const float* bhh[3];
  const float* fcw;
  float* outbuf;
  unsigned short* y[3];
  unsigned* fl;    // [(L*32+s)*4+w]*16 per-producer flags (t+1), fire-and-forget
  unsigned* fcfl;  // [(s*4+w)]*16 layer-2 flags (every 8th step, DRAIN-FREE)
};

__global__ void zero_sync(unsigned* f) {
  int i = blockIdx.x * 256 + threadIdx.x;
  if (i < 8192) f[i] = 0;
}

// sentinel pre-fill of all y buffers (agent scope -> LLC)
__global__ void fill_y(u64* p) {
  const u64 pat = 0x7F807F807F807F80ull;
  size_t g = (size_t)blockIdx.x * 256 + threadIdx.x;
#pragma unroll
  for (int i = 0; i < 16; ++i)
    __hip_atomic_store(p + g + (size_t)i * 393216, pat, __ATOMIC_RELAXED,
                       __HIP_MEMORY_SCOPE_AGENT);
}

__global__ void bias_init_kernel(const float* __restrict__ fcb, float* __restrict__ out) {
  int i = blockIdx.x * 256 + threadIdx.x;
  if (i < Bb * Cc) out[i] = fcb[i % Cc];
}

// grid 256, 1 block/CU. bid<96: LSTM (L=bid>>5, s=bid&31, 16 dims/slice, per-wave
// batch chains). bid>=96: FC (160 blocks, tiles gated on drain-free fcfl).
// R13 protocol exactly, with the LAST drains removed: layer-2's fcfl release is
// fire-and-forget; FC compensates with mixed-mode reads (plain L2-cacheable y2
// load + sentinel check + sc0sc1 selective re-read — livelock-free since the
// re-read bypasses any sentinel-polluted L2 line).
__launch_bounds__(256, 1)
__global__ void mega_kernel(PT p) {
  const int bid = blockIdx.x;
  const int tid = threadIdx.x;
  const int lane = tid & 63;
  const int w = tid >> 6;
  const int q = lane >> 4;
  const int c = lane & 15;
  const int b = 16 * w + c;

  __shared__ unsigned short Whl[64 * 512];  // 64 KB swizzled (recurrent)
  __shared__ unsigned short Wil[64 * 512];  // 64 KB (input; L0 uses 64x256)

  if (bid < 96) {
    const int L = bid >> 5;
    const int s = bid & 31;
    const int n0 = s * 16;

    const int Kin = (L == 0) ? Ii : Hh;
    {  // stage: LDS row r=tt*16+rho <- gate-row (rho&3)*H + n0 + 4*(rho>>2) + tt
      const float* src = p.Whh[L];
      for (int idx = tid; idx < 64 * 64; idx += 256) {
        int r = idx >> 6, kk = (idx & 63) << 3;
        int rho = r & 15, tt = r >> 4;
        int j = (rho & 3) * Hh + n0 + 4 * (rho >> 2) + tt;
        const float* sr = src + (size_t)j * Hh + kk;
        s8 tv;
#pragma unroll
        for (int e = 0; e < 8; ++e) tv[e] = (short)f2bf(sr[e]);
        int byt = ((r * 512 + kk) * 2) ^ ((r & 7) << 4);
        *(s8*)((char*)Whl + byt) = tv;
      }
      const float* si = p.Wih[L];
      const int kd8 = Kin >> 3;
      for (int idx = tid; idx < 64 * kd8; idx += 256) {
        int r = idx / kd8, kk = (idx - r * kd8) << 3;
        int rho = r & 15, tt = r >> 4;
        int j = (rho & 3) * Hh + n0 + 4 * (rho >> 2) + tt;
        const float* sr = si + (size_t)j * Kin + kk;
        s8 tv;
#pragma unroll
        for (int e = 0; e < 8; ++e) tv[e] = (short)f2bf(sr[e]);
        int byt = ((r * Kin + kk) * 2) ^ ((r & 7) << 4);
        *(s8*)((char*)Wil + byt) = tv;
      }
    }

    f4 bias[4];
#pragma unroll
    for (int tt = 0; tt < 4; ++tt)
#pragma unroll
      for (int g = 0; g < 4; ++g) {
        int bi = g * Hh + n0 + 4 * q + tt;  // lane (q,c) tile tt -> dim n0+4q+tt
        bias[tt][g] = p.bih[L][bi] + p.bhh[L][bi];
      }
    float cst[4] = {0.f, 0.f, 0.f, 0.f};
    __syncthreads();

    const int aswz = (c & 7) << 4;
    unsigned short* yl = p.y[L];
    const unsigned short* ylow = (L > 0) ? p.y[L - 1] : (const unsigned short*)0;
    unsigned* flin = (L > 0) ? p.fl + ((L - 1) * 32) * 4 * 16 : (unsigned*)0;
    unsigned* flown = p.fl + (L * 32) * 4 * 16;
    unsigned* myfl = p.fl + ((L * 32 + s) * 4 + w) * 16;

    for (int t = 0; t < Tt; ++t) {
      f4 acc[4];
#pragma unroll
      for (int tt = 0; tt < 4; ++tt) acc[tt] = bias[tt];

      // ---- input acquisition + GEMM ----
      if (L == 0) {
        const float* xr = p.x + ((size_t)b * Tt + t) * Ii + 8 * q;
#pragma unroll
        for (int kc = 0; kc < 8; ++kc) {
          f4 xa = *(const f4*)(xr + kc * 32);
          f4 xc = *(const f4*)(xr + kc * 32 + 4);
          s8 xb;
#pragma unroll
          for (int e = 0; e < 4; ++e) { xb[e] = (short)f2bf(xa[e]); xb[e + 4] = (short)f2bf(xc[e]); }
#pragma unroll
          for (int tt = 0; tt < 4; ++tt) {
            int byt = (((tt * 16 + c) * 256 + kc * 32 + 8 * q) * 2) ^ aswz;
            s8 wa = *(const s8*)((const char*)Wil + byt);
            acc[tt] = __builtin_amdgcn_mfma_f32_16x16x32_bf16(wa, xb, acc[tt], 0, 0, 0);
          }
        }
      } else {
        // poll 32 producer flags of layer L-1 (this wave index)
        while (!__all(lane < 32
                          ? __hip_atomic_load(flin + (lane * 4 + w) * 16, __ATOMIC_RELAXED,
                                              __HIP_MEMORY_SCOPE_AGENT) >= (unsigned)(t + 1)
                          : true))
          __builtin_amdgcn_s_sleep(1);
        asm volatile("" ::: "memory");
        const unsigned short* yr = ylow + ((size_t)b * Tt + t) * Hh + 8 * q;
        s8 yb[16];
#pragma unroll
        for (int kc = 0; kc < 16; ++kc) yb[kc] = ld128_llc(yr + kc * 32);
        VMCNT0; SBAR;
        while (1) {  // sentinel verify + selective re-read (insurance, rare)
          unsigned bad = 0;
#pragma unroll
          for (int kc = 0; kc < 16; ++kc)
            if (!chk(yb[kc])) bad |= (1u << kc);
          if (__all(bad == 0)) break;
          __builtin_amdgcn_s_sleep(1);
#pragma unroll
          for (int kc = 0; kc < 16; ++kc)
            if (bad & (1u << kc)) yb[kc] = ld128_llc(yr + kc * 32);
          VMCNT0; SBAR;
        }
#pragma unroll
        for (int tt = 0; tt < 4; ++tt)
#pragma unroll
          for (int kc = 0; kc < 16; ++kc) {
            int byt = (((tt * 16 + c) * 512 + kc * 32 + 8 * q) * 2) ^ aswz;
            s8 wa = *(const s8*)((const char*)Wil + byt);
            acc[tt] = __builtin_amdgcn_mfma_f32_16x16x32_bf16(wa, yb[kc], acc[tt], 0, 0, 0);
          }
      }

      // ---- h[t-1]: poll flags -> bulk asm read -> verify -> rec GEMM ----
      if (t > 0) {
        const unsigned short* hr = yl + ((size_t)b * Tt + (t - 1)) * Hh + 8 * q;
        s8 hb[16];
        while (!__all(lane < 32
                          ? __hip_atomic_load(flown + (lane * 4 + w) * 16, __ATOMIC_RELAXED,
                                              __HIP_MEMORY_SCOPE_AGENT) >= (unsigned)t
                          : true))
          __builtin_amdgcn_s_sleep(1);
        asm volatile("" ::: "memory");
#pragma unroll
        for (int kc = 0; kc < 16; ++kc) hb[kc] = ld128_llc(hr + kc * 32);
        VMCNT0; SBAR;
        while (1) {
          unsigned bad = 0;
#pragma unroll
          for (int kc = 0; kc < 16; ++kc)
            if (!chk(hb[kc])) bad |= (1u << kc);
          if (__all(bad == 0)) break;
          __builtin_amdgcn_s_sleep(1);
#pragma unroll
          for (int kc = 0; kc < 16; ++kc)
            if (bad & (1u << kc)) hb[kc] = ld128_llc(hr + kc * 32);
          VMCNT0; SBAR;
        }
#pragma unroll
        for (int tt = 0; tt < 4; ++tt)
#pragma unroll
          for (int kc = 0; kc < 16; ++kc) {
            int byt = (((tt * 16 + c) * 512 + kc * 32 + 8 * q) * 2) ^ aswz;
            s8 wa = *(const s8*)((const char*)Whl + byt);
            acc[tt] = __builtin_amdgcn_mfma_f32_16x16x32_bf16(wa, hb[kc], acc[tt], 0, 0, 0);
          }
      }

      // ---- pointwise: lane (q,c) dims n0+4q+tt, gates {i,f,g,o}=acc[tt][0..3] ----
      unsigned short hu[4];
#pragma unroll
      for (int tt = 0; tt < 4; ++tt) {
        float ii = sigf(acc[tt][0]), ff = sigf(acc[tt][1]);
        float gg = tanhs(acc[tt][2]), oo = sigf(acc[tt][3]);
        cst[tt] = ff * cst[tt] + ii * gg;
        hu[tt] = f2bf(oo * tanhs(cst[tt]));
      }
      u64 hv = (u64)hu[0] | ((u64)hu[1] << 16) | ((u64)hu[2] << 32) | ((u64)hu[3] << 48);
      u64* dst = (u64*)(yl + ((size_t)b * Tt + t) * Hh + n0 + 4 * q);
      // fire-and-forget: h store + flag, NO drain (consumers verify sentinels)
      __hip_atomic_store(dst, hv, __ATOMIC_RELAXED, __HIP_MEMORY_SCOPE_AGENT);
      if (lane == 0) {
        __hip_atomic_store(myfl, (unsigned)(t + 1), __ATOMIC_RELAXED, __HIP_MEMORY_SCOPE_AGENT);
        // layer-2: DRAIN-FREE amortized FC release (FC verifies data itself)
        if (L == 2 && (t & 7) == 7)
          __hip_atomic_store(p.fcfl + (s * 4 + w) * 16, (unsigned)(t + 1), __ATOMIC_RELAXED,
                             __HIP_MEMORY_SCOPE_AGENT);
      }
    }
  } else {
    // ======================= FC role =======================
    const int fcid = bid - 96;
    const int KT = Tt * Hh;
    const unsigned short* y2 = p.y[2];
    for (int ti = fcid; ti < 1024; ti += 160) {
      const int kch = ti >> 5, ct = ti & 31;
      const unsigned tneed1 = (unsigned)(kch * 8 + 8);  // fcfl value releasing this k-chunk
      bool ok;
      do {
        unsigned v = 0xFFFFFFFFu;
        if (lane < 32) {
          unsigned mn = 0xFFFFFFFFu;
#pragma unroll
          for (int ww = 0; ww < 4; ++ww) {
            unsigned vv = __hip_atomic_load(p.fcfl + (lane * 4 + ww) * 16, __ATOMIC_RELAXED,
                                            __HIP_MEMORY_SCOPE_AGENT);
            mn = mn < vv ? mn : vv;
          }
          v = mn;
        }
        ok = __all(v >= tneed1);
        if (!ok) __builtin_amdgcn_s_sleep(16);
      } while (!ok);
      asm volatile("" ::: "memory");

      const int kbase = kch * 4096 + q * 8;
      const int c0 = ct * 32 + c;
      const int c1 = c0 + 16;
      const bool v0 = (c0 < Cc), v1 = (c1 < Cc);
      const float* w0 = p.fcw + (size_t)c0 * KT;
      const float* w1 = p.fcw + (size_t)c1 * KT;
      const unsigned short* yr = y2 + (size_t)b * KT;
      f4 a0 = {0.f, 0.f, 0.f, 0.f}, a1 = {0.f, 0.f, 0.f, 0.f};
      for (int kk = 0; kk < 4096; kk += 32) {
        const int k = kbase + kk;
        // mixed-mode read: plain (L2-cacheable) + sentinel check + sc1 re-read.
        // Livelock-free: the re-read bypasses any sentinel-polluted L2 line.
        s8 bf = *(const s8*)(yr + k);
        while (!__all(chk(bf))) {
          __builtin_amdgcn_s_sleep(1);
          bf = ld128_llc(yr + k);
          VMCNT0; SBAR;
        }
        s8 wa0 = {0, 0, 0, 0, 0, 0, 0, 0}, wa1 = {0, 0, 0, 0, 0, 0, 0, 0};
        if (v0) {
#pragma unroll
          for (int qq = 0; qq < 8; ++qq) wa0[qq] = (short)f2bf(w0[k + qq]);
        }
        if (v1) {
#pragma unroll
          for (int qq = 0; qq < 8; ++qq) wa1[qq] = (short)f2bf(w1[k + qq]);
        }
        a0 = __builtin_amdgcn_mfma_f32_16x16x32_bf16(wa0, bf, a0, 0, 0, 0);
        a1 = __builtin_amdgcn_mfma_f32_16x16x32_bf16(wa1, bf, a1, 0, 0, 0);
      }
      const int rr = q * 4;
#pragma unroll
      for (int qq = 0; qq < 4; ++qq) {
        int ca = ct * 32 + rr + qq;
        if (ca < Cc) atomicAdd(p.outbuf + (size_t)b * Cc + ca, a0[qq]);
        int cb2 = ca + 16;
        if (cb2 < Cc) atomicAdd(p.outbuf + (size_t)b * Cc + cb2, a1[qq]);
      }
    }
  }
}

extern "C" void kernel_launch(void* const* d_in, const int* in_sizes, int n_in,
                              void* d_out, int out_size, void* d_ws, size_t ws_size,
                              hipStream_t stream) {
  PT p;
  p.x = (const float*)d_in[0];
  p.Wih[0] = (const float*)d_in[1];  p.Whh[0] = (const float*)d_in[2];
  p.bih[0] = (const float*)d_in[3];  p.bhh[0] = (const float*)d_in[4];
  p.Wih[1] = (const float*)d_in[5];  p.Whh[1] = (const float*)d_in[6];
  p.bih[1] = (const float*)d_in[7];  p.bhh[1] = (const float*)d_in[8];
  p.Wih[2] = (const float*)d_in[9];  p.Whh[2] = (const float*)d_in[10];
  p.bih[2] = (const float*)d_in[11]; p.bhh[2] = (const float*)d_in[12];
  p.fcw = (const float*)d_in[13];
  const float* fcb = (const float*)d_in[14];
  p.outbuf = (float*)d_out;

  char* ws = (char*)d_ws;
  p.fl = (unsigned*)ws;                 // 24 KB spread flags
  p.fcfl = p.fl + 6144;                 // 8 KB fc gates
  const size_t ysz = (size_t)Bb * Tt * Hh;
  unsigned short* y0 = (unsigned short*)(ws + 65536);
  p.y[0] = y0;
  p.y[1] = y0 + ysz;
  p.y[2] = y0 + 2 * ysz;

  zero_sync<<<32, 256, 0, stream>>>(p.fl);
  fill_y<<<1536, 256, 0, stream>>>((u64*)y0);  // 3*ysz*2 B = 6291456 u64 exactly
  bias_init_kernel<<<250, 256, 0, stream>>>(fcb, (float*)d_out);
  mega_kernel<<<256, 256, 0, stream>>>(p);
}

// Round 19
// 1760.944 us; speedup vs baseline: 1.4144x; 1.0196x over previous
//
#include <hip/hip_runtime.h>
#include <hip/hip_bf16.h>

#define Bb 64
#define Tt 256
#define Ii 256
#define Hh 512
#define Cc 1000
#define SENT 0x7F80u  // bf16 +inf; |h|<1 so never produced

typedef float f4 __attribute__((ext_vector_type(4)));
typedef short s8 __attribute__((ext_vector_type(8)));
typedef unsigned long long u64;

__device__ __forceinline__ unsigned short f2bf(float f) {
  union { float f; unsigned u; } v; v.f = f;
  return (unsigned short)((v.u + 0x7FFFu + ((v.u >> 16) & 1u)) >> 16);
}
__device__ __forceinline__ float sigf(float x) {
  return __builtin_amdgcn_rcpf(1.f + __expf(-x));
}
__device__ __forceinline__ float tanhs(float x) {
  float ax = fabsf(x);
  float e = __expf(-2.f * ax);
  float r = (1.f - e) * __builtin_amdgcn_rcpf(1.f + e);
  return copysignf(r, x);
}

// LLC load (bypass L1+L2) — R8/R13-proven; sentinel re-reads never see stale cache.
__device__ __forceinline__ s8 ld128_llc(const unsigned short* p) {
  s8 v;
  asm volatile("global_load_dwordx4 %0, %1, off sc0 sc1" : "=&v"(v) : "v"(p) : "memory");
  return v;
}
#define VMCNT0 asm volatile("s_waitcnt vmcnt(0)" ::: "memory")
#define SBAR __builtin_amdgcn_sched_barrier(0)

__device__ __forceinline__ bool chk(s8 v) {  // both 8B halves non-sentinel
  return ((unsigned short)v[0] != (unsigned short)SENT) &
         ((unsigned short)v[4] != (unsigned short)SENT);
}

struct PT {
  const float* x;
  const float* Whh[3]; const float* Wih[3];
  const float* bih[3]; const float* bhh[3];
  const float* fcw;
  float* outbuf;
  unsigned short* y[3];
  unsigned* fl;    // [(L*32+s)*4+w]*16 per-producer flags (t+1), fire-and-forget
  unsigned* fcfl;  // [(s*4+w)]*16 layer-2 drained flags (every 8th step)
};

__global__ void zero_sync(unsigned* f) {
  int i = blockIdx.x * 256 + threadIdx.x;
  if (i < 8192) f[i] = 0;
}

// sentinel pre-fill of all y buffers (agent scope -> LLC)
__global__ void fill_y(u64* p) {
  const u64 pat = 0x7F807F807F807F80ull;
  size_t g = (size_t)blockIdx.x * 256 + threadIdx.x;
#pragma unroll
  for (int i = 0; i < 16; ++i)
    __hip_atomic_store(p + g + (size_t)i * 393216, pat, __ATOMIC_RELAXED,
                       __HIP_MEMORY_SCOPE_AGENT);
}

__global__ void bias_init_kernel(const float* __restrict__ fcb, float* __restrict__ out) {
  int i = blockIdx.x * 256 + threadIdx.x;
  if (i < Bb * Cc) out[i] = fcb[i % Cc];
}

// grid 256, 1 block/CU. bid<96: LSTM (L=bid>>5, s=bid&31, 16 dims/slice, per-wave
// batch chains). bid>=96: FC (160 blocks, tiles gated on fcfl).
// R13 protocol exactly; ONE structural change: the loop is software-pipelined so
// the input phase (y-wait/read/GEMM for step t+1) runs AFTER h[t] is stored —
// the y-phase executes while h[t] propagates to consumers, taking it off the
// h->h critical cycle. Numerics identical (acc order: bias -> yGEMM -> hGEMM).
__launch_bounds__(256, 1)
__global__ void mega_kernel(PT p) {
  const int bid = blockIdx.x;
  const int tid = threadIdx.x;
  const int lane = tid & 63;
  const int w = tid >> 6;
  const int q = lane >> 4;
  const int c = lane & 15;
  const int b = 16 * w + c;

  __shared__ unsigned short Whl[64 * 512];  // 64 KB swizzled (recurrent)
  __shared__ unsigned short Wil[64 * 512];  // 64 KB (input; L0 uses 64x256)

  if (bid < 96) {
    const int L = bid >> 5;
    const int s = bid & 31;
    const int n0 = s * 16;

    const int Kin = (L == 0) ? Ii : Hh;
    {  // stage: LDS row r=tt*16+rho <- gate-row (rho&3)*H + n0 + 4*(rho>>2) + tt
      const float* src = p.Whh[L];
      for (int idx = tid; idx < 64 * 64; idx += 256) {
        int r = idx >> 6, kk = (idx & 63) << 3;
        int rho = r & 15, tt = r >> 4;
        int j = (rho & 3) * Hh + n0 + 4 * (rho >> 2) + tt;
        const float* sr = src + (size_t)j * Hh + kk;
        s8 tv;
#pragma unroll
        for (int e = 0; e < 8; ++e) tv[e] = (short)f2bf(sr[e]);
        int byt = ((r * 512 + kk) * 2) ^ ((r & 7) << 4);
        *(s8*)((char*)Whl + byt) = tv;
      }
      const float* si = p.Wih[L];
      const int kd8 = Kin >> 3;
      for (int idx = tid; idx < 64 * kd8; idx += 256) {
        int r = idx / kd8, kk = (idx - r * kd8) << 3;
        int rho = r & 15, tt = r >> 4;
        int j = (rho & 3) * Hh + n0 + 4 * (rho >> 2) + tt;
        const float* sr = si + (size_t)j * Kin + kk;
        s8 tv;
#pragma unroll
        for (int e = 0; e < 8; ++e) tv[e] = (short)f2bf(sr[e]);
        int byt = ((r * Kin + kk) * 2) ^ ((r & 7) << 4);
        *(s8*)((char*)Wil + byt) = tv;
      }
    }

    f4 bias[4];
#pragma unroll
    for (int tt = 0; tt < 4; ++tt)
#pragma unroll
      for (int g = 0; g < 4; ++g) {
        int bi = g * Hh + n0 + 4 * q + tt;  // lane (q,c) tile tt -> dim n0+4q+tt
        bias[tt][g] = p.bih[L][bi] + p.bhh[L][bi];
      }
    float cst[4] = {0.f, 0.f, 0.f, 0.f};
    __syncthreads();

    const int aswz = (c & 7) << 4;
    unsigned short* yl = p.y[L];
    const unsigned short* ylow = (L > 0) ? p.y[L - 1] : (const unsigned short*)0;
    unsigned* flin = (L > 0) ? p.fl + ((L - 1) * 32) * 4 * 16 : (unsigned*)0;
    unsigned* flown = p.fl + (L * 32) * 4 * 16;
    unsigned* myfl = p.fl + ((L * 32 + s) * 4 + w) * 16;

    f4 acc[4];

    // ================= prologue: acc = bias + inputGEMM(t=0) =================
#pragma unroll
    for (int tt = 0; tt < 4; ++tt) acc[tt] = bias[tt];
    if (L == 0) {
      const float* xr = p.x + ((size_t)b * Tt + 0) * Ii + 8 * q;
#pragma unroll
      for (int kc = 0; kc < 8; ++kc) {
        f4 xa = *(const f4*)(xr + kc * 32);
        f4 xc = *(const f4*)(xr + kc * 32 + 4);
        s8 xb;
#pragma unroll
        for (int e = 0; e < 4; ++e) { xb[e] = (short)f2bf(xa[e]); xb[e + 4] = (short)f2bf(xc[e]); }
#pragma unroll
        for (int tt = 0; tt < 4; ++tt) {
          int byt = (((tt * 16 + c) * 256 + kc * 32 + 8 * q) * 2) ^ aswz;
          s8 wa = *(const s8*)((const char*)Wil + byt);
          acc[tt] = __builtin_amdgcn_mfma_f32_16x16x32_bf16(wa, xb, acc[tt], 0, 0, 0);
        }
      }
    } else {
      while (!__all(lane < 32
                        ? __hip_atomic_load(flin + (lane * 4 + w) * 16, __ATOMIC_RELAXED,
                                            __HIP_MEMORY_SCOPE_AGENT) >= 1u
                        : true))
        __builtin_amdgcn_s_sleep(1);
      asm volatile("" ::: "memory");
      const unsigned short* yr = ylow + ((size_t)b * Tt + 0) * Hh + 8 * q;
      s8 yb[16];
#pragma unroll
      for (int kc = 0; kc < 16; ++kc) yb[kc] = ld128_llc(yr + kc * 32);
      VMCNT0; SBAR;
      while (1) {
        unsigned bad = 0;
#pragma unroll
        for (int kc = 0; kc < 16; ++kc)
          if (!chk(yb[kc])) bad |= (1u << kc);
        if (__all(bad == 0)) break;
        __builtin_amdgcn_s_sleep(1);
#pragma unroll
        for (int kc = 0; kc < 16; ++kc)
          if (bad & (1u << kc)) yb[kc] = ld128_llc(yr + kc * 32);
        VMCNT0; SBAR;
      }
#pragma unroll
      for (int tt = 0; tt < 4; ++tt)
#pragma unroll
        for (int kc = 0; kc < 16; ++kc) {
          int byt = (((tt * 16 + c) * 512 + kc * 32 + 8 * q) * 2) ^ aswz;
          s8 wa = *(const s8*)((const char*)Wil + byt);
          acc[tt] = __builtin_amdgcn_mfma_f32_16x16x32_bf16(wa, yb[kc], acc[tt], 0, 0, 0);
        }
    }

    // ================= main loop (input phase pipelined to t+1) ==============
    for (int t = 0; t < Tt; ++t) {
      // ---- h[t-1]: poll flags -> bulk asm read -> verify -> rec GEMM ----
      if (t > 0) {
        const unsigned short* hr = yl + ((size_t)b * Tt + (t - 1)) * Hh + 8 * q;
        s8 hb[16];
        while (!__all(lane < 32
                          ? __hip_atomic_load(flown + (lane * 4 + w) * 16, __ATOMIC_RELAXED,
                                              __HIP_MEMORY_SCOPE_AGENT) >= (unsigned)t
                          : true))
          __builtin_amdgcn_s_sleep(1);
        asm volatile("" ::: "memory");
#pragma unroll
        for (int kc = 0; kc < 16; ++kc) hb[kc] = ld128_llc(hr + kc * 32);
        VMCNT0; SBAR;
        while (1) {
          unsigned bad = 0;
#pragma unroll
          for (int kc = 0; kc < 16; ++kc)
            if (!chk(hb[kc])) bad |= (1u << kc);
          if (__all(bad == 0)) break;
          __builtin_amdgcn_s_sleep(1);
#pragma unroll
          for (int kc = 0; kc < 16; ++kc)
            if (bad & (1u << kc)) hb[kc] = ld128_llc(hr + kc * 32);
          VMCNT0; SBAR;
        }
#pragma unroll
        for (int tt = 0; tt < 4; ++tt)
#pragma unroll
          for (int kc = 0; kc < 16; ++kc) {
            int byt = (((tt * 16 + c) * 512 + kc * 32 + 8 * q) * 2) ^ aswz;
            s8 wa = *(const s8*)((const char*)Whl + byt);
            acc[tt] = __builtin_amdgcn_mfma_f32_16x16x32_bf16(wa, hb[kc], acc[tt], 0, 0, 0);
          }
      }

      // ---- pointwise + h store + flag (the h->h cycle ends here) ----
      unsigned short hu[4];
#pragma unroll
      for (int tt = 0; tt < 4; ++tt) {
        float ii = sigf(acc[tt][0]), ff = sigf(acc[tt][1]);
        float gg = tanhs(acc[tt][2]), oo = sigf(acc[tt][3]);
        cst[tt] = ff * cst[tt] + ii * gg;
        hu[tt] = f2bf(oo * tanhs(cst[tt]));
      }
      u64 hv = (u64)hu[0] | ((u64)hu[1] << 16) | ((u64)hu[2] << 32) | ((u64)hu[3] << 48);
      u64* dst = (u64*)(yl + ((size_t)b * Tt + t) * Hh + n0 + 4 * q);
      __hip_atomic_store(dst, hv, __ATOMIC_RELAXED, __HIP_MEMORY_SCOPE_AGENT);
      if (lane == 0)
        __hip_atomic_store(myfl, (unsigned)(t + 1), __ATOMIC_RELAXED, __HIP_MEMORY_SCOPE_AGENT);
      // layer-2 only: amortized drained release for FC (sound gate, every 8 steps)
      if (L == 2 && (t & 7) == 7) {
        VMCNT0;
        if (lane == 0)
          __hip_atomic_store(p.fcfl + (s * 4 + w) * 16, (unsigned)(t + 1), __ATOMIC_RELAXED,
                             __HIP_MEMORY_SCOPE_AGENT);
      }

      // ---- input phase for t+1 (runs while h[t] propagates to consumers) ----
      if (t + 1 < Tt) {
#pragma unroll
        for (int tt = 0; tt < 4; ++tt) acc[tt] = bias[tt];
        if (L == 0) {
          const float* xr = p.x + ((size_t)b * Tt + (t + 1)) * Ii + 8 * q;
#pragma unroll
          for (int kc = 0; kc < 8; ++kc) {
            f4 xa = *(const f4*)(xr + kc * 32);
            f4 xc = *(const f4*)(xr + kc * 32 + 4);
            s8 xb;
#pragma unroll
            for (int e = 0; e < 4; ++e) { xb[e] = (short)f2bf(xa[e]); xb[e + 4] = (short)f2bf(xc[e]); }
#pragma unroll
            for (int tt = 0; tt < 4; ++tt) {
              int byt = (((tt * 16 + c) * 256 + kc * 32 + 8 * q) * 2) ^ aswz;
              s8 wa = *(const s8*)((const char*)Wil + byt);
              acc[tt] = __builtin_amdgcn_mfma_f32_16x16x32_bf16(wa, xb, acc[tt], 0, 0, 0);
            }
          }
        } else {
          while (!__all(lane < 32
                            ? __hip_atomic_load(flin + (lane * 4 + w) * 16, __ATOMIC_RELAXED,
                                                __HIP_MEMORY_SCOPE_AGENT) >= (unsigned)(t + 2)
                            : true))
            __builtin_amdgcn_s_sleep(1);
          asm volatile("" ::: "memory");
          const unsigned short* yr = ylow + ((size_t)b * Tt + (t + 1)) * Hh + 8 * q;
          s8 yb[16];
#pragma unroll
          for (int kc = 0; kc < 16; ++kc) yb[kc] = ld128_llc(yr + kc * 32);
          VMCNT0; SBAR;
          while (1) {
            unsigned bad = 0;
#pragma unroll
            for (int kc = 0; kc < 16; ++kc)
              if (!chk(yb[kc])) bad |= (1u << kc);
            if (__all(bad == 0)) break;
            __builtin_amdgcn_s_sleep(1);
#pragma unroll
            for (int kc = 0; kc < 16; ++kc)
              if (bad & (1u << kc)) yb[kc] = ld128_llc(yr + kc * 32);
            VMCNT0; SBAR;
          }
#pragma unroll
          for (int tt = 0; tt < 4; ++tt)
#pragma unroll
            for (int kc = 0; kc < 16; ++kc) {
              int byt = (((tt * 16 + c) * 512 + kc * 32 + 8 * q) * 2) ^ aswz;
              s8 wa = *(const s8*)((const char*)Wil + byt);
              acc[tt] = __builtin_amdgcn_mfma_f32_16x16x32_bf16(wa, yb[kc], acc[tt], 0, 0, 0);
            }
        }
      }
    }
  } else {
    // ======================= FC role =======================
    const int fcid = bid - 96;
    const int KT = Tt * Hh;
    const unsigned short* y2 = p.y[2];
    for (int ti = fcid; ti < 1024; ti += 160) {
      const int kch = ti >> 5, ct = ti & 31;
      const unsigned tneed1 = (unsigned)(kch * 8 + 8);  // fcfl value releasing this k-chunk
      bool ok;
      do {
        unsigned v = 0xFFFFFFFFu;
        if (lane < 32) {
          unsigned mn = 0xFFFFFFFFu;
#pragma unroll
          for (int ww = 0; ww < 4; ++ww) {
            unsigned vv = __hip_atomic_load(p.fcfl + (lane * 4 + ww) * 16, __ATOMIC_RELAXED,
                                            __HIP_MEMORY_SCOPE_AGENT);
            mn = mn < vv ? mn : vv;
          }
          v = mn;
        }
        ok = __all(v >= tneed1);
        if (!ok) __builtin_amdgcn_s_sleep(16);
      } while (!ok);
      asm volatile("" ::: "memory");

      const int kbase = kch * 4096 + q * 8;
      const int c0 = ct * 32 + c;
      const int c1 = c0 + 16;
      const bool v0 = (c0 < Cc), v1 = (c1 < Cc);
      const float* w0 = p.fcw + (size_t)c0 * KT;
      const float* w1 = p.fcw + (size_t)c1 * KT;
      const unsigned short* yr = y2 + (size_t)b * KT;
      f4 a0 = {0.f, 0.f, 0.f, 0.f}, a1 = {0.f, 0.f, 0.f, 0.f};
      for (int kk = 0; kk < 4096; kk += 32) {
        const int k = kbase + kk;
        s8 bf = *(const s8*)(yr + k);
        s8 wa0 = {0, 0, 0, 0, 0, 0, 0, 0}, wa1 = {0, 0, 0, 0, 0, 0, 0, 0};
        if (v0) {
#pragma unroll
          for (int qq = 0; qq < 8; ++qq) wa0[qq] = (short)f2bf(w0[k + qq]);
        }
        if (v1) {
#pragma unroll
          for (int qq = 0; qq < 8; ++qq) wa1[qq] = (short)f2bf(w1[k + qq]);
        }
        a0 = __builtin_amdgcn_mfma_f32_16x16x32_bf16(wa0, bf, a0, 0, 0, 0);
        a1 = __builtin_amdgcn_mfma_f32_16x16x32_bf16(wa1, bf, a1, 0, 0, 0);
      }
      const int rr = q * 4;
#pragma unroll
      for (int qq = 0; qq < 4; ++qq) {
        int ca = ct * 32 + rr + qq;
        if (ca < Cc) atomicAdd(p.outbuf + (size_t)b * Cc + ca, a0[qq]);
        int cb2 = ca + 16;
        if (cb2 < Cc) atomicAdd(p.outbuf + (size_t)b * Cc + cb2, a1[qq]);
      }
    }
  }
}

extern "C" void kernel_launch(void* const* d_in, const int* in_sizes, int n_in,
                              void* d_out, int out_size, void* d_ws, size_t ws_size,
                              hipStream_t stream) {
  PT p;
  p.x = (const float*)d_in[0];
  p.Wih[0] = (const float*)d_in[1];  p.Whh[0] = (const float*)d_in[2];
  p.bih[0] = (const float*)d_in[3];  p.bhh[0] = (const float*)d_in[4];
  p.Wih[1] = (const float*)d_in[5];  p.Whh[1] = (const float*)d_in[6];
  p.bih[1] = (const float*)d_in[7];  p.bhh[1] = (const float*)d_in[8];
  p.Wih[2] = (const float*)d_in[9];  p.Whh[2] = (const float*)d_in[10];
  p.bih[2] = (const float*)d_in[11]; p.bhh[2] = (const float*)d_in[12];
  p.fcw = (const float*)d_in[13];
  const float* fcb = (const float*)d_in[14];
  p.outbuf = (float*)d_out;

  char* ws = (char*)d_ws;
  p.fl = (unsigned*)ws;                 // 24 KB spread flags
  p.fcfl = p.fl + 6144;                 // 8 KB fc gates
  const size_t ysz = (size_t)Bb * Tt * Hh;
  unsigned short* y0 = (unsigned short*)(ws + 65536);
  p.y[0] = y0;
  p.y[1] = y0 + ysz;
  p.y[2] = y0 + 2 * ysz;

  zero_sync<<<32, 256, 0, stream>>>(p.fl);
  fill_y<<<1536, 256, 0, stream>>>((u64*)y0);  // 3*ysz*2 B = 6291456 u64 exactly
  bias_init_kernel<<<250, 256, 0, stream>>>(fcb, (float*)d_out);
  mega_kernel<<<256, 256, 0, stream>>>(p);
}